// Round 5
// baseline (636.498 us; speedup 1.0000x reference)
//
#include <hip/hip_runtime.h>
#include <hip/hip_bf16.h>
#include <hip/hip_fp16.h>

// Problem constants (match reference)
static constexpr int CH     = 128;   // IN_CH == HID
static constexpr int NCLS   = 32;
static constexpr int NGRAPH = 256;

// Bucketed CSR build: buckets are 512-node ranges (bucket = dst >> 9).
static constexpr int BSHIFT = 9;
static constexpr int BW     = 1 << BSHIFT;   // 512 nodes per bucket
static constexpr int MAXB   = 256;

// ---------------------------------------------------------------------------
// 1) bucket histogram (LDS-aggregated)
// ---------------------------------------------------------------------------
__global__ __launch_bounds__(256) void k_hist(const int* __restrict__ dst,
                                              int* __restrict__ gbcnt, int E) {
  __shared__ int h[MAXB];
  int t = threadIdx.x;
  h[t] = 0;
  __syncthreads();
  for (int i = blockIdx.x * 256 + t; i < E; i += gridDim.x * 256)
    atomicAdd(&h[dst[i] >> BSHIFT], 1);
  __syncthreads();
  if (h[t]) atomicAdd(&gbcnt[t], h[t]);
}

// ---------------------------------------------------------------------------
// 2) scan bucket counts -> ebase[257]; init bucket cursors
// ---------------------------------------------------------------------------
__global__ __launch_bounds__(256) void k_bscan(const int* __restrict__ gbcnt,
                                               int* __restrict__ ebase,
                                               int* __restrict__ gcur) {
  __shared__ int s[MAXB];
  int t = threadIdx.x;
  int v0 = gbcnt[t];
  s[t] = v0;
  __syncthreads();
  for (int st = 1; st < MAXB; st <<= 1) {
    int v = (t >= st) ? s[t - st] : 0;
    __syncthreads();
    s[t] += v;
    __syncthreads();
  }
  int ex = s[t] - v0;
  ebase[t] = ex;
  gcur[t]  = ex;
  if (t == MAXB - 1) ebase[MAXB] = s[t];
}

// ---------------------------------------------------------------------------
// 3) scatter (src,dst) pairs into bucket-ordered edge array
// ---------------------------------------------------------------------------
__global__ __launch_bounds__(1024) void k_scatter(
    const int* __restrict__ src, const int* __restrict__ dst,
    int* __restrict__ gcur, int2* __restrict__ ebuf, int E) {
  __shared__ int bcnt[MAXB];
  __shared__ int bbase[MAXB];
  int t = threadIdx.x;
  if (t < MAXB) bcnt[t] = 0;
  __syncthreads();
  int base = blockIdx.x * 8192;
  int s_[8], d_[8], r_[8];
  #pragma unroll
  for (int j = 0; j < 8; ++j) {
    int i = base + j * 1024 + t;
    if (i < E) {
      s_[j] = src[i];
      d_[j] = dst[i];
      r_[j] = atomicAdd(&bcnt[d_[j] >> BSHIFT], 1);
    }
  }
  __syncthreads();
  if (t < MAXB && bcnt[t]) bbase[t] = atomicAdd(&gcur[t], bcnt[t]);
  __syncthreads();
  #pragma unroll
  for (int j = 0; j < 8; ++j) {
    int i = base + j * 1024 + t;
    if (i < E) {
      int b = d_[j] >> BSHIFT;
      ebuf[bbase[b] + r_[j]] = make_int2(s_[j], d_[j]);
    }
  }
}

// ---------------------------------------------------------------------------
// 4) per-bucket CSR build
// ---------------------------------------------------------------------------
__global__ __launch_bounds__(1024) void k_build(
    const int2* __restrict__ ebuf, const int* __restrict__ ebase,
    int* __restrict__ offs, float* __restrict__ dinv,
    int* __restrict__ csr, int N, int E, int NBUCK) {
  __shared__ int sdeg[BW];
  __shared__ int sscan[BW];
  int b = blockIdx.x;
  int t = threadIdx.x;
  int lo = b << BSHIFT;
  int e0 = ebase[b], e1 = ebase[b + 1];

  if (t < BW) sdeg[t] = 0;
  __syncthreads();
  for (int e = e0 + t; e < e1; e += 1024)
    atomicAdd(&sdeg[ebuf[e].y - lo], 1);
  __syncthreads();
  if (t < BW) sscan[t] = sdeg[t];
  __syncthreads();
  for (int st = 1; st < BW; st <<= 1) {
    int v = (t < BW && t >= st) ? sscan[t - st] : 0;
    __syncthreads();
    if (t < BW) sscan[t] += v;
    __syncthreads();
  }
  if (t < BW) {
    int ex = e0 + sscan[t] - sdeg[t];
    int n = lo + t;
    if (n < N) {
      offs[n] = ex;
      dinv[n] = 1.0f / sqrtf((float)(sdeg[t] + 1));
    }
    sscan[t] = ex;
  }
  if (b == NBUCK - 1 && t == 0) offs[N] = E;
  __syncthreads();
  for (int e = e0 + t; e < e1; e += 1024) {
    int2 p = ebuf[e];
    int pos = atomicAdd(&sscan[p.y - lo], 1);
    csr[pos] = p.x;
  }
}

// ---------------------------------------------------------------------------
// 5) sort each node's adjacency list by src (perf-only: phase-aligned L2
//    locality in k_agg). Wave-per-node bitonic sort, <=128 entries in 2
//    regs/lane. deg>128 (prob ~0 for Poisson(32)) skipped: correctness
//    does not depend on order.
// ---------------------------------------------------------------------------
__global__ __launch_bounds__(256) void k_sortadj(
    int* __restrict__ csr, const int* __restrict__ offs, int N) {
  int node = blockIdx.x * 4 + (threadIdx.x >> 6);
  int lane = threadIdx.x & 63;
  if (node >= N) return;
  int beg = offs[node], end = offs[node + 1];
  int deg = end - beg;
  if (deg <= 1 || deg > 128) return;
  const int PAD = 0x7fffffff;
  int v0 = (lane < deg)      ? csr[beg + lane]      : PAD;   // element e0 = lane
  int v1 = (64 + lane < deg) ? csr[beg + 64 + lane] : PAD;   // element e1 = lane+64
  #pragma unroll
  for (int k = 2; k <= 128; k <<= 1) {
    #pragma unroll
    for (int j = k >> 1; j > 0; j >>= 1) {
      if (j == 64) {
        // partner across slots, same lane; k==128 here, both ascending
        int mn = min(v0, v1), mx = max(v0, v1);
        v0 = mn; v1 = mx;
      } else {
        int e0 = lane, e1 = 64 + lane;
        int p0 = __shfl_xor(v0, j, 64);
        int p1 = __shfl_xor(v1, j, 64);
        bool low0 = ((e0 & j) == 0), asc0 = ((e0 & k) == 0);
        bool low1 = ((e1 & j) == 0), asc1 = ((e1 & k) == 0);
        int mn0 = min(v0, p0), mx0 = max(v0, p0);
        int mn1 = min(v1, p1), mx1 = max(v1, p1);
        v0 = (low0 == asc0) ? mn0 : mx0;
        v1 = (low1 == asc1) ? mn1 : mx1;
      }
    }
  }
  if (lane < deg)      csr[beg + lane]      = v0;
  if (64 + lane < deg) csr[beg + 64 + lane] = v1;
}

// ---------------------------------------------------------------------------
// GEMM: C[r][:] = half( (A[r][:] @ W) * dinv[r] )     A:[M,128] fp32, C fp16
// ---------------------------------------------------------------------------
__global__ __launch_bounds__(256) void k_gemm_scale(
    const float* __restrict__ A, const float* __restrict__ W,
    const float* __restrict__ dinv, __half* __restrict__ C, int M) {
  __shared__ float As[128][33];
  __shared__ float Bs[32][128];
  int tid = threadIdx.x;
  int tx = tid & 15, ty = tid >> 4;
  int row0 = blockIdx.x * 128;
  float acc[8][8];
  #pragma unroll
  for (int i = 0; i < 8; ++i)
    #pragma unroll
    for (int j = 0; j < 8; ++j) acc[i][j] = 0.0f;

  for (int k0 = 0; k0 < CH; k0 += 32) {
    #pragma unroll
    for (int l = 0; l < 4; ++l) {
      int i = tid + l * 256;
      int r = i >> 3, c4 = (i & 7) << 2;
      int rr = row0 + r; if (rr >= M) rr = M - 1;
      float4 v = *(const float4*)(A + (size_t)rr * CH + k0 + c4);
      As[r][c4 + 0] = v.x; As[r][c4 + 1] = v.y;
      As[r][c4 + 2] = v.z; As[r][c4 + 3] = v.w;
    }
    #pragma unroll
    for (int l = 0; l < 4; ++l) {
      int i = tid + l * 256;
      int r = i >> 5, c4 = (i & 31) << 2;
      *(float4*)&Bs[r][c4] = *(const float4*)(W + (size_t)(k0 + r) * CH + c4);
    }
    __syncthreads();
    #pragma unroll
    for (int kk = 0; kk < 32; ++kk) {
      float a[8];
      #pragma unroll
      for (int i = 0; i < 8; ++i) a[i] = As[ty * 8 + i][kk];
      float4 b0 = *(const float4*)&Bs[kk][tx * 8];
      float4 b1 = *(const float4*)&Bs[kk][tx * 8 + 4];
      float b[8] = {b0.x, b0.y, b0.z, b0.w, b1.x, b1.y, b1.z, b1.w};
      #pragma unroll
      for (int i = 0; i < 8; ++i)
        #pragma unroll
        for (int j = 0; j < 8; ++j) acc[i][j] = fmaf(a[i], b[j], acc[i][j]);
    }
    __syncthreads();
  }
  #pragma unroll
  for (int i = 0; i < 8; ++i) {
    int r = row0 + ty * 8 + i;
    if (r < M) {
      float d = dinv[r];
      __half2 p0 = __floats2half2_rn(acc[i][0] * d, acc[i][1] * d);
      __half2 p1 = __floats2half2_rn(acc[i][2] * d, acc[i][3] * d);
      __half2 p2 = __floats2half2_rn(acc[i][4] * d, acc[i][5] * d);
      __half2 p3 = __floats2half2_rn(acc[i][6] * d, acc[i][7] * d);
      float4 ov;
      ((__half2*)&ov)[0] = p0; ((__half2*)&ov)[1] = p1;
      ((__half2*)&ov)[2] = p2; ((__half2*)&ov)[3] = p3;
      *((float4*)(C + (size_t)r * CH) + tx) = ov;   // 16B = 8 halfs
    }
  }
}

// ---------------------------------------------------------------------------
// Aggregation (pull, CSR)
// ---------------------------------------------------------------------------
__global__ __launch_bounds__(256) void k_agg(
    const __half* __restrict__ xs, const int* __restrict__ csr,
    const int* __restrict__ offs, const float* __restrict__ dinv,
    const float* __restrict__ bias, float* __restrict__ out, int N) {
  int node = blockIdx.x * 4 + (threadIdx.x >> 6);
  int lane = threadIdx.x & 63;
  if (node >= N) return;
  int beg = offs[node], end = offs[node + 1];
  const __half2* base = (const __half2*)xs;
  float2 self = __half22float2(base[(size_t)node * 64 + lane]);
  float ax = self.x, ay = self.y;
  float bx2 = 0.f, by2 = 0.f;
  int e = beg;
  for (; e + 3 < end; e += 4) {
    int s0 = csr[e], s1 = csr[e + 1], s2 = csr[e + 2], s3 = csr[e + 3];
    float2 v0 = __half22float2(base[(size_t)s0 * 64 + lane]);
    float2 v1 = __half22float2(base[(size_t)s1 * 64 + lane]);
    float2 v2 = __half22float2(base[(size_t)s2 * 64 + lane]);
    float2 v3 = __half22float2(base[(size_t)s3 * 64 + lane]);
    ax += v0.x + v2.x; ay += v0.y + v2.y;
    bx2 += v1.x + v3.x; by2 += v1.y + v3.y;
  }
  for (; e < end; ++e) {
    int s = csr[e];
    float2 v = __half22float2(base[(size_t)s * 64 + lane]);
    ax += v.x; ay += v.y;
  }
  ax += bx2; ay += by2;
  float d = dinv[node];
  float rx = fmaf(ax, d, bias[2 * lane]);
  float ry = fmaf(ay, d, bias[2 * lane + 1]);
  float2 r = {fmaxf(rx, 0.f), fmaxf(ry, 0.f)};
  ((float2*)out)[(size_t)node * 64 + lane] = r;
}

// ---------------------------------------------------------------------------
// Pool: batch sorted -> run-length accumulate, few atomics
// ---------------------------------------------------------------------------
__global__ __launch_bounds__(128) void k_pool(
    const float* __restrict__ h, const int* __restrict__ batch,
    float* __restrict__ gsum, int N) {
  int ch = threadIdx.x;
  int n0 = blockIdx.x * 128;
  int n1 = n0 + 128; if (n1 > N) n1 = N;
  if (n0 >= N) return;
  float acc = 0.f;
  int curg = batch[n0];
  for (int n = n0; n < n1; ++n) {
    int g = batch[n];
    if (g != curg) {
      atomicAdd(&gsum[curg * CH + ch], acc);
      acc = 0.f; curg = g;
    }
    acc += h[(size_t)n * CH + ch];
  }
  atomicAdd(&gsum[curg * CH + ch], acc);
}

// ---------------------------------------------------------------------------
// Graph run boundaries (batch is sorted; no atomics).
// ---------------------------------------------------------------------------
__global__ __launch_bounds__(256) void k_gbound(
    const int* __restrict__ batch, int* __restrict__ gstart,
    int* __restrict__ gend, int N) {
  int i = blockIdx.x * 256 + threadIdx.x;
  if (i >= N) return;
  int g = batch[i];
  if (i == 0 || batch[i - 1] != g) gstart[g] = i;
  if (i == N - 1 || batch[i + 1] != g) gend[g] = i + 1;
}

// ---------------------------------------------------------------------------
// FC
// ---------------------------------------------------------------------------
__global__ __launch_bounds__(64) void k_fc(
    const float* __restrict__ gsum, const int* __restrict__ gstart,
    const int* __restrict__ gend, const float* __restrict__ Wfc,
    const float* __restrict__ bfc, float* __restrict__ outp) {
  int g = blockIdx.x;
  int j = threadIdx.x;
  if (j >= NCLS) return;
  int cnt = gend[g] - gstart[g];
  float invc = 1.0f / fmaxf((float)cnt, 1.0f);
  float acc = 0.0f;
  for (int c = 0; c < CH; ++c)
    acc = fmaf(gsum[g * CH + c], Wfc[c * NCLS + j], acc);
  outp[g * NCLS + j] = fmaf(acc, invc, bfc[j]);
}

// ---------------------------------------------------------------------------
extern "C" void kernel_launch(void* const* d_in, const int* in_sizes, int n_in,
                              void* d_out, int out_size, void* d_ws, size_t ws_size,
                              hipStream_t stream) {
  const float* x    = (const float*)d_in[0];
  const int*   ei   = (const int*)d_in[1];
  const int*   batch= (const int*)d_in[2];
  const float* W1   = (const float*)d_in[3];
  const float* b1   = (const float*)d_in[4];
  const float* W2   = (const float*)d_in[5];
  const float* b2   = (const float*)d_in[6];
  const float* Wfc  = (const float*)d_in[7];
  const float* bfc  = (const float*)d_in[8];
  float* outp = (float*)d_out;

  const int N = in_sizes[0] / CH;       // 100000
  const int E = in_sizes[1] / 2;        // 3200000
  const int* src = ei;
  const int* dst = ei + E;
  const int NBUCK = (N + BW - 1) >> BSHIFT;   // 196

  // Workspace carve (256B aligned)
  char* w = (char*)d_ws;
  size_t o = 0;
  auto carve = [&](size_t bytes) -> void* {
    o = (o + 255) & ~(size_t)255;
    void* p = w + o;
    o += bytes;
    return p;
  };
  int*    offs   = (int*)   carve((size_t)(N + 1) * 4);
  int*    gbcnt  = (int*)   carve(MAXB * 4);
  int*    ebase  = (int*)   carve((MAXB + 1) * 4);
  int*    gcur   = (int*)   carve(MAXB * 4);
  int*    csr    = (int*)   carve((size_t)E * 4);
  float*  dinv   = (float*) carve((size_t)N * 4);
  __half* xsbuf  = (__half*)carve((size_t)N * CH * 2);  // fp16 gather buffer
  float*  hbuf   = (float*) carve((size_t)N * CH * 4);  // fp32 h between stages
  float*  gsum   = (float*) carve((size_t)NGRAPH * CH * 4);
  int*    gstart = (int*)   carve((size_t)NGRAPH * 4);
  int*    gend   = (int*)   carve((size_t)NGRAPH * 4);
  (void)ws_size;

  // ebuf aliases hbuf (dead until agg layer-1 writes it): needs E*8 = 25.6MB
  int2* ebuf = (int2*)hbuf;

  hipMemsetAsync(gbcnt,  0, MAXB * 4, stream);
  hipMemsetAsync(gsum,   0, (size_t)NGRAPH * CH * 4, stream);
  hipMemsetAsync(gstart, 0, (size_t)NGRAPH * 4, stream);
  hipMemsetAsync(gend,   0, (size_t)NGRAPH * 4, stream);

  // CSR build (bucketed counting sort) + per-node src-sort
  k_hist   <<<512, 256, 0, stream>>>(dst, gbcnt, E);
  k_bscan  <<<1, MAXB, 0, stream>>>(gbcnt, ebase, gcur);
  k_scatter<<<(E + 8191) / 8192, 1024, 0, stream>>>(src, dst, gcur, ebuf, E);
  k_build  <<<NBUCK, 1024, 0, stream>>>(ebuf, ebase, offs, dinv, csr, N, E, NBUCK);

  const int GB = (N + 127) / 128;
  const int AB = (N + 3) / 4;
  const int NB = (N + 255) / 256;

  k_sortadj<<<AB, 256, 0, stream>>>(csr, offs, N);

  // Layer 1: xs = fp16((x@W1)*dinv) ; h = relu(agg(xs)*dinv + b1)  (fp32)
  k_gemm_scale<<<GB, 256, 0, stream>>>(x, W1, dinv, xsbuf, N);
  k_agg<<<AB, 256, 0, stream>>>(xsbuf, csr, offs, dinv, b1, hbuf, N);
  // Layer 2
  k_gemm_scale<<<GB, 256, 0, stream>>>(hbuf, W2, dinv, xsbuf, N);
  k_agg<<<AB, 256, 0, stream>>>(xsbuf, csr, offs, dinv, b2, hbuf, N);

  // Pool + FC
  k_pool<<<GB, 128, 0, stream>>>(hbuf, batch, gsum, N);
  k_gbound<<<NB, 256, 0, stream>>>(batch, gstart, gend, N);
  k_fc<<<NGRAPH, 64, 0, stream>>>(gsum, gstart, gend, Wfc, bfc, outp);
  (void)out_size; (void)n_in;
}

// Round 6
// 531.436 us; speedup vs baseline: 1.1977x; 1.1977x over previous
//
#include <hip/hip_runtime.h>
#include <hip/hip_bf16.h>
#include <hip/hip_fp16.h>

// Problem constants (match reference)
static constexpr int CH     = 128;   // IN_CH == HID
static constexpr int NCLS   = 32;
static constexpr int NGRAPH = 256;

// Bucketed CSR build: buckets are 512-node ranges (bucket = dst >> 9).
static constexpr int BSHIFT = 9;
static constexpr int BW     = 1 << BSHIFT;   // 512 nodes per bucket
static constexpr int MAXB   = 256;

typedef _Float16 half8 __attribute__((ext_vector_type(8)));
typedef float    f32x4 __attribute__((ext_vector_type(4)));

// ---------------------------------------------------------------------------
// 1) bucket histogram (LDS-aggregated)
// ---------------------------------------------------------------------------
__global__ __launch_bounds__(256) void k_hist(const int* __restrict__ dst,
                                              int* __restrict__ gbcnt, int E) {
  __shared__ int h[MAXB];
  int t = threadIdx.x;
  h[t] = 0;
  __syncthreads();
  for (int i = blockIdx.x * 256 + t; i < E; i += gridDim.x * 256)
    atomicAdd(&h[dst[i] >> BSHIFT], 1);
  __syncthreads();
  if (h[t]) atomicAdd(&gbcnt[t], h[t]);
}

// ---------------------------------------------------------------------------
// 2) scan bucket counts -> ebase[257]; init bucket cursors
// ---------------------------------------------------------------------------
__global__ __launch_bounds__(256) void k_bscan(const int* __restrict__ gbcnt,
                                               int* __restrict__ ebase,
                                               int* __restrict__ gcur) {
  __shared__ int s[MAXB];
  int t = threadIdx.x;
  int v0 = gbcnt[t];
  s[t] = v0;
  __syncthreads();
  for (int st = 1; st < MAXB; st <<= 1) {
    int v = (t >= st) ? s[t - st] : 0;
    __syncthreads();
    s[t] += v;
    __syncthreads();
  }
  int ex = s[t] - v0;
  ebase[t] = ex;
  gcur[t]  = ex;
  if (t == MAXB - 1) ebase[MAXB] = s[t];
}

// ---------------------------------------------------------------------------
// 3) scatter (src,dst) pairs into bucket-ordered edge array
// ---------------------------------------------------------------------------
__global__ __launch_bounds__(1024) void k_scatter(
    const int* __restrict__ src, const int* __restrict__ dst,
    int* __restrict__ gcur, int2* __restrict__ ebuf, int E) {
  __shared__ int bcnt[MAXB];
  __shared__ int bbase[MAXB];
  int t = threadIdx.x;
  if (t < MAXB) bcnt[t] = 0;
  __syncthreads();
  int base = blockIdx.x * 8192;
  int s_[8], d_[8], r_[8];
  #pragma unroll
  for (int j = 0; j < 8; ++j) {
    int i = base + j * 1024 + t;
    if (i < E) {
      s_[j] = src[i];
      d_[j] = dst[i];
      r_[j] = atomicAdd(&bcnt[d_[j] >> BSHIFT], 1);
    }
  }
  __syncthreads();
  if (t < MAXB && bcnt[t]) bbase[t] = atomicAdd(&gcur[t], bcnt[t]);
  __syncthreads();
  #pragma unroll
  for (int j = 0; j < 8; ++j) {
    int i = base + j * 1024 + t;
    if (i < E) {
      int b = d_[j] >> BSHIFT;
      ebuf[bbase[b] + r_[j]] = make_int2(s_[j], d_[j]);
    }
  }
}

// ---------------------------------------------------------------------------
// 4) per-bucket CSR build
// ---------------------------------------------------------------------------
__global__ __launch_bounds__(1024) void k_build(
    const int2* __restrict__ ebuf, const int* __restrict__ ebase,
    int* __restrict__ offs, float* __restrict__ dinv,
    int* __restrict__ csr, int N, int E, int NBUCK) {
  __shared__ int sdeg[BW];
  __shared__ int sscan[BW];
  int b = blockIdx.x;
  int t = threadIdx.x;
  int lo = b << BSHIFT;
  int e0 = ebase[b], e1 = ebase[b + 1];

  if (t < BW) sdeg[t] = 0;
  __syncthreads();
  for (int e = e0 + t; e < e1; e += 1024)
    atomicAdd(&sdeg[ebuf[e].y - lo], 1);
  __syncthreads();
  if (t < BW) sscan[t] = sdeg[t];
  __syncthreads();
  for (int st = 1; st < BW; st <<= 1) {
    int v = (t < BW && t >= st) ? sscan[t - st] : 0;
    __syncthreads();
    if (t < BW) sscan[t] += v;
    __syncthreads();
  }
  if (t < BW) {
    int ex = e0 + sscan[t] - sdeg[t];
    int n = lo + t;
    if (n < N) {
      offs[n] = ex;
      dinv[n] = 1.0f / sqrtf((float)(sdeg[t] + 1));
    }
    sscan[t] = ex;
  }
  if (b == NBUCK - 1 && t == 0) offs[N] = E;
  __syncthreads();
  for (int e = e0 + t; e < e1; e += 1024) {
    int2 p = ebuf[e];
    int pos = atomicAdd(&sscan[p.y - lo], 1);
    csr[pos] = p.x;
  }
}

// ---------------------------------------------------------------------------
// MFMA GEMM: C[r][:] = fp16( (A[r][:] @ W) * dinv[r] )   A fp32 [M,128],
// W fp32 [128,128], C fp16. Single K=128 shot, 256 threads = 4 waves,
// wave handles 32 rows. A and W^T staged to fp16 LDS, rows padded to 136
// halfs (ds_read_b128 spreads evenly across all 32 banks).
// ---------------------------------------------------------------------------
__global__ __launch_bounds__(256) void k_gemm_scale(
    const float* __restrict__ A, const float* __restrict__ W,
    const float* __restrict__ dinv, __half* __restrict__ C, int M) {
  __shared__ _Float16 As[128][136];
  __shared__ _Float16 WsT[128][136];   // WsT[n][k] = W[k][n]
  int tid = threadIdx.x;
  int row0 = blockIdx.x * 128;

  // stage A: fp32 -> fp16, coalesced reads, 8B LDS stores (2-way = free)
  #pragma unroll
  for (int l = 0; l < 16; ++l) {
    int idx = tid + l * 256;            // 0..4095 float4 slots
    int r = idx >> 5, c4 = (idx & 31) << 2;
    int rr = row0 + r; if (rr >= M) rr = M - 1;
    float4 v = *(const float4*)(A + (size_t)rr * CH + c4);
    As[r][c4 + 0] = (_Float16)v.x; As[r][c4 + 1] = (_Float16)v.y;
    As[r][c4 + 2] = (_Float16)v.z; As[r][c4 + 3] = (_Float16)v.w;
  }
  // stage W transposed (scalar LDS stores; once per block, cost negligible)
  #pragma unroll
  for (int l = 0; l < 16; ++l) {
    int idx = tid + l * 256;
    int k = idx >> 5, n4 = (idx & 31) << 2;
    float4 v = *(const float4*)(W + (size_t)k * CH + n4);
    WsT[n4 + 0][k] = (_Float16)v.x; WsT[n4 + 1][k] = (_Float16)v.y;
    WsT[n4 + 2][k] = (_Float16)v.z; WsT[n4 + 3][k] = (_Float16)v.w;
  }
  __syncthreads();

  int lane = tid & 63, wave = tid >> 6;
  int quad = lane >> 4, sub = lane & 15;
  int m0 = wave * 32;                   // this wave: rows m0..m0+31

  f32x4 acc[2][8];
  #pragma unroll
  for (int i = 0; i < 2; ++i)
    #pragma unroll
    for (int j = 0; j < 8; ++j) acc[i][j] = (f32x4){0.f, 0.f, 0.f, 0.f};

  #pragma unroll
  for (int kc = 0; kc < 4; ++kc) {
    int ko = kc * 32 + quad * 8;        // k-offset of this lane's 8 elements
    half8 a0 = *(const half8*)&As[m0 + sub][ko];
    half8 a1 = *(const half8*)&As[m0 + 16 + sub][ko];
    #pragma unroll
    for (int nt = 0; nt < 8; ++nt) {
      half8 b = *(const half8*)&WsT[nt * 16 + sub][ko];
      acc[0][nt] = __builtin_amdgcn_mfma_f32_16x16x32_f16(a0, b, acc[0][nt], 0, 0, 0);
      acc[1][nt] = __builtin_amdgcn_mfma_f32_16x16x32_f16(a1, b, acc[1][nt], 0, 0, 0);
    }
  }

  // epilogue: D lane mapping col=sub, row=quad*4+reg
  #pragma unroll
  for (int mt = 0; mt < 2; ++mt) {
    #pragma unroll
    for (int r = 0; r < 4; ++r) {
      int row = row0 + m0 + mt * 16 + quad * 4 + r;
      if (row < M) {
        float d = dinv[row];
        #pragma unroll
        for (int nt = 0; nt < 8; ++nt) {
          int col = nt * 16 + sub;
          C[(size_t)row * CH + col] = __float2half(acc[mt][nt][r] * d);
        }
      }
    }
  }
}

// ---------------------------------------------------------------------------
// Aggregation (pull, CSR)
// ---------------------------------------------------------------------------
__global__ __launch_bounds__(256) void k_agg(
    const __half* __restrict__ xs, const int* __restrict__ csr,
    const int* __restrict__ offs, const float* __restrict__ dinv,
    const float* __restrict__ bias, float* __restrict__ out, int N) {
  int node = blockIdx.x * 4 + (threadIdx.x >> 6);
  int lane = threadIdx.x & 63;
  if (node >= N) return;
  int beg = offs[node], end = offs[node + 1];
  const __half2* base = (const __half2*)xs;
  float2 self = __half22float2(base[(size_t)node * 64 + lane]);
  float ax = self.x, ay = self.y;
  float bx2 = 0.f, by2 = 0.f;
  int e = beg;
  for (; e + 3 < end; e += 4) {
    int s0 = csr[e], s1 = csr[e + 1], s2 = csr[e + 2], s3 = csr[e + 3];
    float2 v0 = __half22float2(base[(size_t)s0 * 64 + lane]);
    float2 v1 = __half22float2(base[(size_t)s1 * 64 + lane]);
    float2 v2 = __half22float2(base[(size_t)s2 * 64 + lane]);
    float2 v3 = __half22float2(base[(size_t)s3 * 64 + lane]);
    ax += v0.x + v2.x; ay += v0.y + v2.y;
    bx2 += v1.x + v3.x; by2 += v1.y + v3.y;
  }
  for (; e < end; ++e) {
    int s = csr[e];
    float2 v = __half22float2(base[(size_t)s * 64 + lane]);
    ax += v.x; ay += v.y;
  }
  ax += bx2; ay += by2;
  float d = dinv[node];
  float rx = fmaf(ax, d, bias[2 * lane]);
  float ry = fmaf(ay, d, bias[2 * lane + 1]);
  float2 r = {fmaxf(rx, 0.f), fmaxf(ry, 0.f)};
  ((float2*)out)[(size_t)node * 64 + lane] = r;
}

// ---------------------------------------------------------------------------
// Pool: batch sorted -> run-length accumulate, few atomics
// ---------------------------------------------------------------------------
__global__ __launch_bounds__(128) void k_pool(
    const float* __restrict__ h, const int* __restrict__ batch,
    float* __restrict__ gsum, int N) {
  int ch = threadIdx.x;
  int n0 = blockIdx.x * 128;
  int n1 = n0 + 128; if (n1 > N) n1 = N;
  if (n0 >= N) return;
  float acc = 0.f;
  int curg = batch[n0];
  for (int n = n0; n < n1; ++n) {
    int g = batch[n];
    if (g != curg) {
      atomicAdd(&gsum[curg * CH + ch], acc);
      acc = 0.f; curg = g;
    }
    acc += h[(size_t)n * CH + ch];
  }
  atomicAdd(&gsum[curg * CH + ch], acc);
}

// ---------------------------------------------------------------------------
// Graph run boundaries (batch is sorted; no atomics).
// ---------------------------------------------------------------------------
__global__ __launch_bounds__(256) void k_gbound(
    const int* __restrict__ batch, int* __restrict__ gstart,
    int* __restrict__ gend, int N) {
  int i = blockIdx.x * 256 + threadIdx.x;
  if (i >= N) return;
  int g = batch[i];
  if (i == 0 || batch[i - 1] != g) gstart[g] = i;
  if (i == N - 1 || batch[i + 1] != g) gend[g] = i + 1;
}

// ---------------------------------------------------------------------------
// FC
// ---------------------------------------------------------------------------
__global__ __launch_bounds__(64) void k_fc(
    const float* __restrict__ gsum, const int* __restrict__ gstart,
    const int* __restrict__ gend, const float* __restrict__ Wfc,
    const float* __restrict__ bfc, float* __restrict__ outp) {
  int g = blockIdx.x;
  int j = threadIdx.x;
  if (j >= NCLS) return;
  int cnt = gend[g] - gstart[g];
  float invc = 1.0f / fmaxf((float)cnt, 1.0f);
  float acc = 0.0f;
  for (int c = 0; c < CH; ++c)
    acc = fmaf(gsum[g * CH + c], Wfc[c * NCLS + j], acc);
  outp[g * NCLS + j] = fmaf(acc, invc, bfc[j]);
}

// ---------------------------------------------------------------------------
extern "C" void kernel_launch(void* const* d_in, const int* in_sizes, int n_in,
                              void* d_out, int out_size, void* d_ws, size_t ws_size,
                              hipStream_t stream) {
  const float* x    = (const float*)d_in[0];
  const int*   ei   = (const int*)d_in[1];
  const int*   batch= (const int*)d_in[2];
  const float* W1   = (const float*)d_in[3];
  const float* b1   = (const float*)d_in[4];
  const float* W2   = (const float*)d_in[5];
  const float* b2   = (const float*)d_in[6];
  const float* Wfc  = (const float*)d_in[7];
  const float* bfc  = (const float*)d_in[8];
  float* outp = (float*)d_out;

  const int N = in_sizes[0] / CH;       // 100000
  const int E = in_sizes[1] / 2;        // 3200000
  const int* src = ei;
  const int* dst = ei + E;
  const int NBUCK = (N + BW - 1) >> BSHIFT;   // 196

  // Workspace carve (256B aligned)
  char* w = (char*)d_ws;
  size_t o = 0;
  auto carve = [&](size_t bytes) -> void* {
    o = (o + 255) & ~(size_t)255;
    void* p = w + o;
    o += bytes;
    return p;
  };
  int*    offs   = (int*)   carve((size_t)(N + 1) * 4);
  int*    gbcnt  = (int*)   carve(MAXB * 4);
  int*    ebase  = (int*)   carve((MAXB + 1) * 4);
  int*    gcur   = (int*)   carve(MAXB * 4);
  int*    csr    = (int*)   carve((size_t)E * 4);
  float*  dinv   = (float*) carve((size_t)N * 4);
  __half* xsbuf  = (__half*)carve((size_t)N * CH * 2);  // fp16 gather buffer
  float*  hbuf   = (float*) carve((size_t)N * CH * 4);  // fp32 h between stages
  float*  gsum   = (float*) carve((size_t)NGRAPH * CH * 4);
  int*    gstart = (int*)   carve((size_t)NGRAPH * 4);
  int*    gend   = (int*)   carve((size_t)NGRAPH * 4);
  (void)ws_size;

  // ebuf aliases hbuf (dead until agg layer-1 writes it): needs E*8 = 25.6MB
  int2* ebuf = (int2*)hbuf;

  hipMemsetAsync(gbcnt,  0, MAXB * 4, stream);
  hipMemsetAsync(gsum,   0, (size_t)NGRAPH * CH * 4, stream);
  hipMemsetAsync(gstart, 0, (size_t)NGRAPH * 4, stream);
  hipMemsetAsync(gend,   0, (size_t)NGRAPH * 4, stream);

  // CSR build (bucketed counting sort)
  k_hist   <<<512, 256, 0, stream>>>(dst, gbcnt, E);
  k_bscan  <<<1, MAXB, 0, stream>>>(gbcnt, ebase, gcur);
  k_scatter<<<(E + 8191) / 8192, 1024, 0, stream>>>(src, dst, gcur, ebuf, E);
  k_build  <<<NBUCK, 1024, 0, stream>>>(ebuf, ebase, offs, dinv, csr, N, E, NBUCK);

  const int GB = (N + 127) / 128;
  const int AB = (N + 3) / 4;
  const int NB = (N + 255) / 256;

  // Layer 1: xs = fp16((x@W1)*dinv) ; h = relu(agg(xs)*dinv + b1)  (fp32)
  k_gemm_scale<<<GB, 256, 0, stream>>>(x, W1, dinv, xsbuf, N);
  k_agg<<<AB, 256, 0, stream>>>(xsbuf, csr, offs, dinv, b1, hbuf, N);
  // Layer 2
  k_gemm_scale<<<GB, 256, 0, stream>>>(hbuf, W2, dinv, xsbuf, N);
  k_agg<<<AB, 256, 0, stream>>>(xsbuf, csr, offs, dinv, b2, hbuf, N);

  // Pool + FC
  k_pool<<<GB, 128, 0, stream>>>(hbuf, batch, gsum, N);
  k_gbound<<<NB, 256, 0, stream>>>(batch, gstart, gend, N);
  k_fc<<<NGRAPH, 64, 0, stream>>>(gsum, gstart, gend, Wfc, bfc, outp);
  (void)out_size; (void)n_in;
}

// Round 7
// 508.665 us; speedup vs baseline: 1.2513x; 1.0448x over previous
//
#include <hip/hip_runtime.h>
#include <hip/hip_bf16.h>
#include <hip/hip_fp16.h>

// Problem constants (match reference)
static constexpr int CH     = 128;   // IN_CH == HID
static constexpr int NCLS   = 32;
static constexpr int NGRAPH = 256;

// Bucketed CSR build: buckets are 512-node ranges (bucket = dst >> 9).
static constexpr int BSHIFT = 9;
static constexpr int BW     = 1 << BSHIFT;   // 512 nodes per bucket
static constexpr int MAXB   = 256;

typedef _Float16 half8 __attribute__((ext_vector_type(8)));
typedef float    f32x4 __attribute__((ext_vector_type(4)));

// ---------------------------------------------------------------------------
// 1) bucket histogram (LDS-aggregated)
// ---------------------------------------------------------------------------
__global__ __launch_bounds__(256) void k_hist(const int* __restrict__ dst,
                                              int* __restrict__ gbcnt, int E) {
  __shared__ int h[MAXB];
  int t = threadIdx.x;
  h[t] = 0;
  __syncthreads();
  for (int i = blockIdx.x * 256 + t; i < E; i += gridDim.x * 256)
    atomicAdd(&h[dst[i] >> BSHIFT], 1);
  __syncthreads();
  if (h[t]) atomicAdd(&gbcnt[t], h[t]);
}

// ---------------------------------------------------------------------------
// 2) scan bucket counts -> ebase[257]; init bucket cursors
// ---------------------------------------------------------------------------
__global__ __launch_bounds__(256) void k_bscan(const int* __restrict__ gbcnt,
                                               int* __restrict__ ebase,
                                               int* __restrict__ gcur) {
  __shared__ int s[MAXB];
  int t = threadIdx.x;
  int v0 = gbcnt[t];
  s[t] = v0;
  __syncthreads();
  for (int st = 1; st < MAXB; st <<= 1) {
    int v = (t >= st) ? s[t - st] : 0;
    __syncthreads();
    s[t] += v;
    __syncthreads();
  }
  int ex = s[t] - v0;
  ebase[t] = ex;
  gcur[t]  = ex;
  if (t == MAXB - 1) ebase[MAXB] = s[t];
}

// ---------------------------------------------------------------------------
// 3) scatter packed edges into bucket-ordered array.
//    pack = (dstlo << 17) | src   (dstlo < 512 -> 9 bits; src < 2^17)
// ---------------------------------------------------------------------------
__global__ __launch_bounds__(1024) void k_scatter(
    const int* __restrict__ src, const int* __restrict__ dst,
    int* __restrict__ gcur, int* __restrict__ ebuf, int E) {
  __shared__ int bcnt[MAXB];
  __shared__ int bbase[MAXB];
  int t = threadIdx.x;
  if (t < MAXB) bcnt[t] = 0;
  __syncthreads();
  int base = blockIdx.x * 8192;
  int s_[8], d_[8], r_[8];
  #pragma unroll
  for (int j = 0; j < 8; ++j) {
    int i = base + j * 1024 + t;
    if (i < E) {
      s_[j] = src[i];
      d_[j] = dst[i];
      r_[j] = atomicAdd(&bcnt[d_[j] >> BSHIFT], 1);
    }
  }
  __syncthreads();
  if (t < MAXB && bcnt[t]) bbase[t] = atomicAdd(&gcur[t], bcnt[t]);
  __syncthreads();
  #pragma unroll
  for (int j = 0; j < 8; ++j) {
    int i = base + j * 1024 + t;
    if (i < E) {
      int b = d_[j] >> BSHIFT;
      int p = ((d_[j] & (BW - 1)) << 17) | s_[j];
      ebuf[bbase[b] + r_[j]] = p;
    }
  }
}

// ---------------------------------------------------------------------------
// 4) per-bucket CSR build (packed edges)
// ---------------------------------------------------------------------------
__global__ __launch_bounds__(1024) void k_build(
    const int* __restrict__ ebuf, const int* __restrict__ ebase,
    int* __restrict__ offs, float* __restrict__ dinv,
    int* __restrict__ csr, int N, int E, int NBUCK) {
  __shared__ int sdeg[BW];
  __shared__ int sscan[BW];
  int b = blockIdx.x;
  int t = threadIdx.x;
  int lo = b << BSHIFT;
  int e0 = ebase[b], e1 = ebase[b + 1];

  if (t < BW) sdeg[t] = 0;
  __syncthreads();
  for (int e = e0 + t; e < e1; e += 1024)
    atomicAdd(&sdeg[ebuf[e] >> 17], 1);
  __syncthreads();
  if (t < BW) sscan[t] = sdeg[t];
  __syncthreads();
  for (int st = 1; st < BW; st <<= 1) {
    int v = (t < BW && t >= st) ? sscan[t - st] : 0;
    __syncthreads();
    if (t < BW) sscan[t] += v;
    __syncthreads();
  }
  if (t < BW) {
    int ex = e0 + sscan[t] - sdeg[t];
    int n = lo + t;
    if (n < N) {
      offs[n] = ex;
      dinv[n] = 1.0f / sqrtf((float)(sdeg[t] + 1));
    }
    sscan[t] = ex;
  }
  if (b == NBUCK - 1 && t == 0) offs[N] = E;
  __syncthreads();
  for (int e = e0 + t; e < e1; e += 1024) {
    int p = ebuf[e];
    int pos = atomicAdd(&sscan[p >> 17], 1);
    csr[pos] = p & 0x1FFFF;
  }
}

// ---------------------------------------------------------------------------
// 5) one-shot W -> fp16 transpose: WhT[n][k] = W[k][n]   (64KB, trivial)
// ---------------------------------------------------------------------------
__global__ __launch_bounds__(256) void k_wt(const float* __restrict__ W,
                                            _Float16* __restrict__ WhT) {
  int i = blockIdx.x * 256 + threadIdx.x;   // grid 64 x 256 = 16384
  int k = i >> 7, n = i & 127;
  WhT[n * CH + k] = (_Float16)W[i];
}

// ---------------------------------------------------------------------------
// MFMA GEMM core: As (fp16 LDS, row-padded 136) x Ws (= W^T, fp16 LDS)
// 4 waves x 32 rows, K=128 single shot, epilogue scales by dinv -> fp16.
// ---------------------------------------------------------------------------
__device__ __forceinline__ void gemm_core(
    const _Float16 (*As)[136], const _Float16 (*Ws)[136],
    const float* __restrict__ dinv, __half* __restrict__ C,
    int row0, int M, int tid) {
  int lane = tid & 63, wave = tid >> 6;
  int quad = lane >> 4, sub = lane & 15;
  int m0 = wave * 32;

  f32x4 acc[2][8];
  #pragma unroll
  for (int i = 0; i < 2; ++i)
    #pragma unroll
    for (int j = 0; j < 8; ++j) acc[i][j] = (f32x4){0.f, 0.f, 0.f, 0.f};

  #pragma unroll
  for (int kc = 0; kc < 4; ++kc) {
    int ko = kc * 32 + quad * 8;
    half8 a0 = *(const half8*)&As[m0 + sub][ko];
    half8 a1 = *(const half8*)&As[m0 + 16 + sub][ko];
    #pragma unroll
    for (int nt = 0; nt < 8; ++nt) {
      half8 b = *(const half8*)&Ws[nt * 16 + sub][ko];
      acc[0][nt] = __builtin_amdgcn_mfma_f32_16x16x32_f16(a0, b, acc[0][nt], 0, 0, 0);
      acc[1][nt] = __builtin_amdgcn_mfma_f32_16x16x32_f16(a1, b, acc[1][nt], 0, 0, 0);
    }
  }
  #pragma unroll
  for (int mt = 0; mt < 2; ++mt) {
    #pragma unroll
    for (int r = 0; r < 4; ++r) {
      int row = row0 + m0 + mt * 16 + quad * 4 + r;
      if (row < M) {
        float d = dinv[row];
        #pragma unroll
        for (int nt = 0; nt < 8; ++nt) {
          int col = nt * 16 + sub;
          C[(size_t)row * CH + col] = __float2half(acc[mt][nt][r] * d);
        }
      }
    }
  }
}

__device__ __forceinline__ void stage_w(const _Float16* __restrict__ WhT,
                                        _Float16 (*Ws)[136], int tid) {
  // straight row-major copy of 128x128 halfs, 16B chunks, conflict-free
  #pragma unroll
  for (int l = 0; l < 8; ++l) {
    int idx = tid + l * 256;            // 0..2047 half8 chunks
    int n = idx >> 4, k8 = (idx & 15) << 3;
    *(half8*)&Ws[n][k8] = *(const half8*)(WhT + n * CH + k8);
  }
}

// A input fp32 (layer 1: x)
__global__ __launch_bounds__(256) void k_gemm_f32(
    const float* __restrict__ A, const _Float16* __restrict__ WhT,
    const float* __restrict__ dinv, __half* __restrict__ C, int M) {
  __shared__ _Float16 As[128][136];
  __shared__ _Float16 Ws[128][136];
  int tid = threadIdx.x;
  int row0 = blockIdx.x * 128;
  #pragma unroll
  for (int l = 0; l < 16; ++l) {
    int idx = tid + l * 256;            // 0..4095 float4 slots
    int r = idx >> 5, c4 = (idx & 31) << 2;
    int rr = row0 + r; if (rr >= M) rr = M - 1;
    float4 v = *(const float4*)(A + (size_t)rr * CH + c4);
    As[r][c4 + 0] = (_Float16)v.x; As[r][c4 + 1] = (_Float16)v.y;
    As[r][c4 + 2] = (_Float16)v.z; As[r][c4 + 3] = (_Float16)v.w;
  }
  stage_w(WhT, Ws, tid);
  __syncthreads();
  gemm_core(As, Ws, dinv, C, row0, M, tid);
}

// A input fp16 (layer 2: h)
__global__ __launch_bounds__(256) void k_gemm_f16(
    const _Float16* __restrict__ A, const _Float16* __restrict__ WhT,
    const float* __restrict__ dinv, __half* __restrict__ C, int M) {
  __shared__ _Float16 As[128][136];
  __shared__ _Float16 Ws[128][136];
  int tid = threadIdx.x;
  int row0 = blockIdx.x * 128;
  #pragma unroll
  for (int l = 0; l < 8; ++l) {
    int idx = tid + l * 256;            // 0..2047 half8 chunks
    int r = idx >> 4, c8 = (idx & 15) << 3;
    int rr = row0 + r; if (rr >= M) rr = M - 1;
    *(half8*)&As[r][c8] = *(const half8*)(A + (size_t)rr * CH + c8);
  }
  stage_w(WhT, Ws, tid);
  __syncthreads();
  gemm_core(As, Ws, dinv, C, row0, M, tid);
}

// ---------------------------------------------------------------------------
// Aggregation (pull, CSR): out fp16
// ---------------------------------------------------------------------------
__global__ __launch_bounds__(256) void k_agg(
    const __half* __restrict__ xs, const int* __restrict__ csr,
    const int* __restrict__ offs, const float* __restrict__ dinv,
    const float* __restrict__ bias, __half* __restrict__ out, int N) {
  int node = blockIdx.x * 4 + (threadIdx.x >> 6);
  int lane = threadIdx.x & 63;
  if (node >= N) return;
  int beg = offs[node], end = offs[node + 1];
  const __half2* base = (const __half2*)xs;
  float2 self = __half22float2(base[(size_t)node * 64 + lane]);
  float ax = self.x, ay = self.y;
  float bx2 = 0.f, by2 = 0.f;
  int e = beg;
  for (; e + 3 < end; e += 4) {
    int s0 = csr[e], s1 = csr[e + 1], s2 = csr[e + 2], s3 = csr[e + 3];
    float2 v0 = __half22float2(base[(size_t)s0 * 64 + lane]);
    float2 v1 = __half22float2(base[(size_t)s1 * 64 + lane]);
    float2 v2 = __half22float2(base[(size_t)s2 * 64 + lane]);
    float2 v3 = __half22float2(base[(size_t)s3 * 64 + lane]);
    ax += v0.x + v2.x; ay += v0.y + v2.y;
    bx2 += v1.x + v3.x; by2 += v1.y + v3.y;
  }
  for (; e < end; ++e) {
    int s = csr[e];
    float2 v = __half22float2(base[(size_t)s * 64 + lane]);
    ax += v.x; ay += v.y;
  }
  ax += bx2; ay += by2;
  float d = dinv[node];
  float rx = fmaf(ax, d, bias[2 * lane]);
  float ry = fmaf(ay, d, bias[2 * lane + 1]);
  ((__half2*)out)[(size_t)node * 64 + lane] =
      __floats2half2_rn(fmaxf(rx, 0.f), fmaxf(ry, 0.f));
}

// ---------------------------------------------------------------------------
// Pool: batch sorted -> run-length accumulate, few atomics (h fp16)
// ---------------------------------------------------------------------------
__global__ __launch_bounds__(128) void k_pool(
    const __half* __restrict__ h, const int* __restrict__ batch,
    float* __restrict__ gsum, int N) {
  int ch = threadIdx.x;
  int n0 = blockIdx.x * 128;
  int n1 = n0 + 128; if (n1 > N) n1 = N;
  if (n0 >= N) return;
  float acc = 0.f;
  int curg = batch[n0];
  for (int n = n0; n < n1; ++n) {
    int g = batch[n];
    if (g != curg) {
      atomicAdd(&gsum[curg * CH + ch], acc);
      acc = 0.f; curg = g;
    }
    acc += __half2float(h[(size_t)n * CH + ch]);
  }
  atomicAdd(&gsum[curg * CH + ch], acc);
}

// ---------------------------------------------------------------------------
// Graph run boundaries (batch is sorted; no atomics).
// ---------------------------------------------------------------------------
__global__ __launch_bounds__(256) void k_gbound(
    const int* __restrict__ batch, int* __restrict__ gstart,
    int* __restrict__ gend, int N) {
  int i = blockIdx.x * 256 + threadIdx.x;
  if (i >= N) return;
  int g = batch[i];
  if (i == 0 || batch[i - 1] != g) gstart[g] = i;
  if (i == N - 1 || batch[i + 1] != g) gend[g] = i + 1;
}

// ---------------------------------------------------------------------------
// FC
// ---------------------------------------------------------------------------
__global__ __launch_bounds__(64) void k_fc(
    const float* __restrict__ gsum, const int* __restrict__ gstart,
    const int* __restrict__ gend, const float* __restrict__ Wfc,
    const float* __restrict__ bfc, float* __restrict__ outp) {
  int g = blockIdx.x;
  int j = threadIdx.x;
  if (j >= NCLS) return;
  int cnt = gend[g] - gstart[g];
  float invc = 1.0f / fmaxf((float)cnt, 1.0f);
  float acc = 0.0f;
  for (int c = 0; c < CH; ++c)
    acc = fmaf(gsum[g * CH + c], Wfc[c * NCLS + j], acc);
  outp[g * NCLS + j] = fmaf(acc, invc, bfc[j]);
}

// ---------------------------------------------------------------------------
extern "C" void kernel_launch(void* const* d_in, const int* in_sizes, int n_in,
                              void* d_out, int out_size, void* d_ws, size_t ws_size,
                              hipStream_t stream) {
  const float* x    = (const float*)d_in[0];
  const int*   ei   = (const int*)d_in[1];
  const int*   batch= (const int*)d_in[2];
  const float* W1   = (const float*)d_in[3];
  const float* b1   = (const float*)d_in[4];
  const float* W2   = (const float*)d_in[5];
  const float* b2   = (const float*)d_in[6];
  const float* Wfc  = (const float*)d_in[7];
  const float* bfc  = (const float*)d_in[8];
  float* outp = (float*)d_out;

  const int N = in_sizes[0] / CH;       // 100000
  const int E = in_sizes[1] / 2;        // 3200000
  const int* src = ei;
  const int* dst = ei + E;
  const int NBUCK = (N + BW - 1) >> BSHIFT;   // 196

  // Workspace carve (256B aligned)
  char* w = (char*)d_ws;
  size_t o = 0;
  auto carve = [&](size_t bytes) -> void* {
    o = (o + 255) & ~(size_t)255;
    void* p = w + o;
    o += bytes;
    return p;
  };
  int*      offs   = (int*)     carve((size_t)(N + 1) * 4);
  int*      gbcnt  = (int*)     carve(MAXB * 4);
  int*      ebase  = (int*)     carve((MAXB + 1) * 4);
  int*      gcur   = (int*)     carve(MAXB * 4);
  int*      csr    = (int*)     carve((size_t)E * 4);
  float*    dinv   = (float*)   carve((size_t)N * 4);
  _Float16* WhT1   = (_Float16*)carve((size_t)CH * CH * 2);
  _Float16* WhT2   = (_Float16*)carve((size_t)CH * CH * 2);
  __half*   xsbuf  = (__half*)  carve((size_t)N * CH * 2);  // fp16 gather buffer
  __half*   hbuf   = (__half*)  carve((size_t)N * CH * 2);  // fp16 h
  float*    gsum   = (float*)   carve((size_t)NGRAPH * CH * 4);
  int*      gstart = (int*)     carve((size_t)NGRAPH * 4);
  int*      gend   = (int*)     carve((size_t)NGRAPH * 4);
  (void)ws_size;

  // ebuf (packed edges) aliases hbuf: needs E*4 = 12.8MB <= 25.6MB
  int* ebuf = (int*)hbuf;

  hipMemsetAsync(gbcnt,  0, MAXB * 4, stream);
  hipMemsetAsync(gsum,   0, (size_t)NGRAPH * CH * 4, stream);
  hipMemsetAsync(gstart, 0, (size_t)NGRAPH * 4, stream);
  hipMemsetAsync(gend,   0, (size_t)NGRAPH * 4, stream);

  // CSR build (bucketed counting sort) + weight transposes
  k_hist   <<<512, 256, 0, stream>>>(dst, gbcnt, E);
  k_bscan  <<<1, MAXB, 0, stream>>>(gbcnt, ebase, gcur);
  k_scatter<<<(E + 8191) / 8192, 1024, 0, stream>>>(src, dst, gcur, ebuf, E);
  k_build  <<<NBUCK, 1024, 0, stream>>>(ebuf, ebase, offs, dinv, csr, N, E, NBUCK);
  k_wt     <<<64, 256, 0, stream>>>(W1, WhT1);
  k_wt     <<<64, 256, 0, stream>>>(W2, WhT2);

  const int GB = (N + 127) / 128;
  const int AB = (N + 3) / 4;
  const int NB = (N + 255) / 256;

  // Layer 1: xs = fp16((x@W1)*dinv) ; h = fp16(relu(agg(xs)*dinv + b1))
  k_gemm_f32<<<GB, 256, 0, stream>>>(x, WhT1, dinv, xsbuf, N);
  k_agg<<<AB, 256, 0, stream>>>(xsbuf, csr, offs, dinv, b1, hbuf, N);
  // Layer 2
  k_gemm_f16<<<GB, 256, 0, stream>>>((const _Float16*)hbuf, WhT2, dinv, xsbuf, N);
  k_agg<<<AB, 256, 0, stream>>>(xsbuf, csr, offs, dinv, b2, hbuf, N);

  // Pool + FC
  k_pool<<<GB, 128, 0, stream>>>(hbuf, batch, gsum, N);
  k_gbound<<<NB, 256, 0, stream>>>(batch, gstart, gend, N);
  k_fc<<<NGRAPH, 64, 0, stream>>>(gsum, gstart, gend, Wfc, bfc, outp);
  (void)out_size; (void)n_in;
}